// Round 6
// baseline (1930.194 us; speedup 1.0000x reference)
//
#include <hip/hip_runtime.h>
#include <math.h>

#define NT      1024
#define NPIX    16384
#define NSLICES 8
#define NMODES  4
#define OBJW    512

// ---- complex helpers -------------------------------------------------------
__device__ __forceinline__ float2 cmul(float2 a, float2 b) {
    return make_float2(fmaf(a.x, b.x, -a.y * b.y), fmaf(a.x, b.y, a.y * b.x));
}

// 4-bit reversal (constexpr -> folds to literals in unrolled loops)
__host__ __device__ constexpr int BR4(int p) {
    return ((p & 1) << 3) | ((p & 2) << 1) | ((p & 4) >> 1) | ((p & 8) >> 3);
}

// W16^k = exp(-2*pi*i*k/16): (cos, sin) tables
__device__ __constant__ float TWC16[8] = {
    1.0f, 0.923879533f, 0.707106781f, 0.382683432f,
    0.0f, -0.382683432f, -0.707106781f, -0.923879533f };
__device__ __constant__ float TWS16[8] = {
    0.0f, 0.382683432f, 0.707106781f, 0.923879533f,
    1.0f, 0.923879533f, 0.707106781f, 0.382683432f };
// cross-8 stage-A twiddle fA(c) = (c<4) ? 1 : W8^(c-4)
__device__ __constant__ float FA_RE[8] = {1,1,1,1, 1.0f,  0.707106781f,  0.0f, -0.707106781f};
__device__ __constant__ float FA_IM[8] = {0,0,0,0, 0.0f, -0.707106781f, -1.0f, -0.707106781f};

// ---- local 16-point FFT in registers ---------------------------------------
__device__ __forceinline__ void fft16_fwd(float2 v[16]) {
    #pragma unroll
    for (int s = 8; s >= 1; s >>= 1) {
        #pragma unroll
        for (int q = 0; q < 16; q += 2 * s) {
            #pragma unroll
            for (int j = 0; j < s; j++) {
                const int tw = j * (8 / s);
                float2 u = v[q + j], w = v[q + j + s];
                v[q + j] = make_float2(u.x + w.x, u.y + w.y);
                float dx = u.x - w.x, dy = u.y - w.y;
                v[q + j + s] = make_float2(fmaf(dx, TWC16[tw],  dy * TWS16[tw]),
                                           fmaf(dy, TWC16[tw], -dx * TWS16[tw]));
            }
        }
    }
}
__device__ __forceinline__ void fft16_inv(float2 v[16]) {
    #pragma unroll
    for (int s = 1; s <= 8; s <<= 1) {
        #pragma unroll
        for (int q = 0; q < 16; q += 2 * s) {
            #pragma unroll
            for (int j = 0; j < s; j++) {
                const int tw = j * (8 / s);
                float2 u = v[q + j], w = v[q + j + s];
                float2 tv = make_float2(fmaf(w.x, TWC16[tw], -w.y * TWS16[tw]),
                                        fmaf(w.y, TWC16[tw],  w.x * TWS16[tw]));
                v[q + j]     = make_float2(u.x + tv.x, u.y + tv.y);
                v[q + j + s] = make_float2(u.x - tv.x, u.y - tv.y);
            }
        }
    }
}

// ---- cross-thread 8-point FFT over sub-index c (shfl_xor 4,2,1) ------------
__device__ __forceinline__ void cross8_fwd(float2 v[16], int c, float2 fA) {
    const float sA = (c < 4) ? 1.0f : -1.0f;
    const float sB = (c & 2) ? -1.0f : 1.0f;
    const float sC = (c & 1) ? -1.0f : 1.0f;
    const bool rot3 = ((c & 3) == 3);
    #pragma unroll
    for (int p = 0; p < 16; p++) {
        float ox = __shfl_xor(v[p].x, 4), oy = __shfl_xor(v[p].y, 4);
        float ax = fmaf(sA, v[p].x, ox), ay = fmaf(sA, v[p].y, oy);
        float bx = fmaf(ax, fA.x, -ay * fA.y);
        float by = fmaf(ax, fA.y,  ay * fA.x);
        ox = __shfl_xor(bx, 2); oy = __shfl_xor(by, 2);
        float nx = fmaf(sB, bx, ox), ny = fmaf(sB, by, oy);
        float rx = rot3 ?  ny : nx;          // *(-i) for c&3==3
        float ry = rot3 ? -nx : ny;
        ox = __shfl_xor(rx, 1); oy = __shfl_xor(ry, 1);
        v[p].x = fmaf(sC, rx, ox); v[p].y = fmaf(sC, ry, oy);
    }
}
__device__ __forceinline__ void cross8_inv(float2 v[16], int c, float2 fA) {
    const float sA = (c < 4) ? 1.0f : -1.0f;
    const float sB = (c & 2) ? -1.0f : 1.0f;
    const float sC = (c & 1) ? -1.0f : 1.0f;
    const bool rot3 = ((c & 3) == 3);
    #pragma unroll
    for (int p = 0; p < 16; p++) {
        float ox = __shfl_xor(v[p].x, 1), oy = __shfl_xor(v[p].y, 1);
        float nx = fmaf(sC, v[p].x, ox), ny = fmaf(sC, v[p].y, oy);
        float rx = rot3 ? -ny : nx;          // *(+i) for c&3==3
        float ry = rot3 ?  nx : ny;
        ox = __shfl_xor(rx, 2); oy = __shfl_xor(ry, 2);
        float bx = fmaf(sB, rx, ox), by = fmaf(sB, ry, oy);
        float ax = fmaf(bx, fA.x,  by * fA.y);   // * conj(fA)
        float ay = fmaf(by, fA.x, -bx * fA.y);
        ox = __shfl_xor(ax, 4); oy = __shfl_xor(ay, 4);
        v[p].x = fmaf(sA, ax, ox); v[p].y = fmaf(sA, ay, oy);
    }
}

// ---- full 128-point pass ---------------------------------------------------
// Reg i holds element (c + 8i); after fwd, reg p holds k = BR4(p) + 16*br3(c).
// t128p is the PERMUTED twiddle table: t128p[8p+c] = W128^(c*BR4(p)) --
// 8 consecutive float2 per p -> 8 distinct banks x 8-lane broadcast, no
// conflicts, no index math.
__device__ __forceinline__ void pass_fwd(float2 v[16], int c, float2 fA,
                                         const float2* t128p) {
    fft16_fwd(v);
    #pragma unroll
    for (int p = 0; p < 16; p++)
        v[p] = cmul(v[p], t128p[8 * p + c]);
    cross8_fwd(v, c, fA);
}
__device__ __forceinline__ void pass_inv(float2 v[16], int c, float2 fA,
                                         const float2* t128p) {
    cross8_inv(v, c, fA);
    #pragma unroll
    for (int p = 0; p < 16; p++) {
        float2 w = t128p[8 * p + c];
        v[p] = cmul(v[p], make_float2(w.x, -w.y));
    }
    fft16_inv(v);
}

// XOR swizzle for T1 buffer ([kw][r], no padding): col' = col ^ sw1(row)
__device__ __forceinline__ int sw1(int row) {
    return ((row ^ (row >> 4)) & 1) << 3;
}

// ---- main kernel: one block (1024 thr) per scan position -------------------
// The allocator pins 64 VGPRs for this 1024-thread kernel regardless of
// waves-per-eu hints (rounds 3-5). Round 6: fit in 64 instead of fighting --
// acc[16] (16 VGPRs, the main spill source) replaced by direct RMW on d_out
// (same-lane RAW across modes; indices fixed per thread -> race-free).
// Persistent state now ~42 VGPRs: v[16]+px+fA+addressing. No spill expected.
__global__ void
__attribute__((amdgpu_flat_work_group_size(1024, 1024)))
__attribute__((amdgpu_waves_per_eu(4, 4)))
multislice_kernel(const float* __restrict__ probe_re,
                  const float* __restrict__ probe_im,
                  const float* __restrict__ obj_re,
                  const float* __restrict__ obj_im,
                  const int*   __restrict__ positions,
                  float*       __restrict__ out)
{
    __shared__ float2 LT[NPIX];      // 131072 B swizzled transpose buffer
    __shared__ float2 t128p[128];    // permuted W128 twiddle: [8p+c]
    __shared__ float2 pytp[128];     // permuted prop y-factor * 1/16384: [8p+c]

    const int t  = threadIdx.x;
    const int g  = t >> 3;                        // row / column-index [0,128)
    const int c  = t & 7;                         // sub-index in 128-FFT
    const int rc = ((c & 1) << 2) | (c & 2) | ((c & 4) >> 2);   // br3(c)
    const int n  = blockIdx.x;
    const int Y0 = positions[2 * n];
    const int X0 = positions[2 * n + 1];

    if (t < 128) {
        int p_ = t >> 3, c_ = t & 7;
        int rc_ = ((c_ & 1) << 2) | (c_ & 2) | ((c_ & 4) >> 2);
        // twiddle W128^(c*BR4(p)) stored at [8p+c]
        float ang = -2.0f * 3.14159265358979323846f
                    * (float)(c_ * BR4(p_)) / 128.0f;
        float s, cc; __sincosf(ang, &s, &cc);
        t128p[t] = make_float2(cc, s);
        // prop y-factor for kh = BR4(p)+16*br3(c), stored at [8p+c]
        int kh = BR4(p_) + 16 * rc_;
        float fy = (float)(kh < 64 ? kh : kh - 128) * (1.0f / 25.6f);
        float ph = -0.15707963267948966f * fy * fy;
        float ps, pcs; __sincosf(ph, &ps, &pcs);
        pytp[t] = make_float2(pcs * (1.0f / 16384.0f), ps * (1.0f / 16384.0f));
    }
    const float2 fA = make_float2(FA_RE[c], FA_IM[c]);
    float fx = (float)(g < 64 ? g : g - 128) * (1.0f / 25.6f);
    float phx = -0.15707963267948966f * fx * fx;
    float pxs, pxc; __sincosf(phx, &pxs, &pxc);
    const float2 px = make_float2(pxc, pxs);
    __syncthreads();

    const long long base = (long long)n * NPIX;

    float2 v[16];

    for (int m = 0; m < NMODES; m++) {
        __syncthreads();   // protect LT reuse across modes
        #pragma unroll
        for (int i = 0; i < 16; i++) {           // ex = probe[m]*patch(slice0)
            int w  = c + 8 * i;
            int pi = m * NPIX + g * 128 + w;
            float2 pr = make_float2(probe_re[pi], probe_im[pi]);
            int oi = (Y0 + g) * OBJW + X0 + w;
            float2 ob = make_float2(obj_re[oi], obj_im[oi]);
            v[i] = cmul(pr, ob);
        }

        for (int s = 1; s < NSLICES; s++) {
            pass_fwd(v, c, fA, t128p);           // Fw
            #pragma unroll                       // T1 write [kw][r=g]
            for (int p = 0; p < 16; p++) {
                int kw = BR4(p) + 16 * rc;
                LT[kw * 128 + (g ^ sw1(kw))] = v[p];
            }
            __syncthreads();
            #pragma unroll                       // T1 read -> C-state
            for (int i = 0; i < 16; i++)
                v[i] = LT[g * 128 + ((c + 8 * i) ^ sw1(g))];
            __syncthreads();
            pass_fwd(v, c, fA, t128p);           // Fh
            #pragma unroll                       // * prop: (py from LDS)*px
            for (int p = 0; p < 16; p++) {
                float2 pp = cmul(pytp[8 * p + c], px);
                v[p] = cmul(v[p], pp);
            }
            pass_inv(v, c, fA, t128p);           // iFh
            #pragma unroll                       // T2 write [r][kw=g]
            for (int i = 0; i < 16; i++) {
                int r = c + 8 * i;
                int col = g ^ ((r & 7) << 1) ^ ((g >> 4) & 1);
                LT[r * 128 + col] = v[i];
            }
            __syncthreads();
            #pragma unroll                       // T2 read -> R-state(perm)
            for (int p = 0; p < 16; p++) {
                int kw = BR4(p) + 16 * rc;
                int col = kw ^ ((g & 7) << 1) ^ ((kw >> 4) & 1);
                v[p] = LT[g * 128 + col];
            }
            __syncthreads();
            pass_inv(v, c, fA, t128p);           // iFw
            #pragma unroll                       // * patch(slice s)
            for (int i = 0; i < 16; i++) {
                int w  = c + 8 * i;
                int oi = (s * OBJW + Y0 + g) * OBJW + X0 + w;
                float2 ob = make_float2(obj_re[oi], obj_im[oi]);
                v[i] = cmul(v[i], ob);
            }
        }

        // final FFT2: Fw, T1, Fh, then RMW-accumulate |.|^2 into out.
        pass_fwd(v, c, fA, t128p);
        #pragma unroll
        for (int p = 0; p < 16; p++) {
            int kw = BR4(p) + 16 * rc;
            LT[kw * 128 + (g ^ sw1(kw))] = v[p];
        }
        __syncthreads();
        #pragma unroll
        for (int i = 0; i < 16; i++)
            v[i] = LT[g * 128 + ((c + 8 * i) ^ sw1(g))];
        pass_fwd(v, c, fA, t128p);
        // fftshift store: (kh,kw) -> (kh^64, kw^64); kh=BR4(p)+16rc, kw=g.
        // Same thread owns the same 16 out-slots every mode -> plain RMW.
        #pragma unroll
        for (int p = 0; p < 16; p++) {
            int kh = BR4(p) + 16 * rc;
            long long oidx = base + (long long)(((kh ^ 64) << 7) + (g ^ 64));
            float val = fmaf(v[p].x, v[p].x, v[p].y * v[p].y);
            if (m > 0) val += out[oidx];
            out[oidx] = val;
        }
    }
}

extern "C" void kernel_launch(void* const* d_in, const int* in_sizes, int n_in,
                              void* d_out, int out_size, void* d_ws, size_t ws_size,
                              hipStream_t stream) {
    const float* probe_re = (const float*)d_in[0];
    const float* probe_im = (const float*)d_in[1];
    const float* obj_re   = (const float*)d_in[2];
    const float* obj_im   = (const float*)d_in[3];
    const int*   pos      = (const int*)d_in[4];
    float* out = (float*)d_out;

    const int N = out_size / NPIX;   // 512 positions
    multislice_kernel<<<dim3(N), dim3(NT), 0, stream>>>(
        probe_re, probe_im, obj_re, obj_im, pos, out);
}

// Round 7
// 1587.646 us; speedup vs baseline: 1.2158x; 1.2158x over previous
//
#include <hip/hip_runtime.h>
#include <hip/hip_fp16.h>
#include <math.h>

#define NT      1024
#define NPIX    16384
#define NSLICES 8
#define NMODES  4
#define OBJW    512
#define LSTR    136        // padded major stride (half2 units): 136%32=8

// ---- complex helpers -------------------------------------------------------
__device__ __forceinline__ float2 cmul(float2 a, float2 b) {
    return make_float2(fmaf(a.x, b.x, -a.y * b.y), fmaf(a.x, b.y, a.y * b.x));
}

// 4-bit reversal (constexpr -> folds to literals in unrolled loops)
__host__ __device__ constexpr int BR4(int p) {
    return ((p & 1) << 3) | ((p & 2) << 1) | ((p & 4) >> 1) | ((p & 8) >> 3);
}
__host__ __device__ constexpr int BR3(int c) {
    return ((c & 1) << 2) | (c & 2) | ((c & 4) >> 2);
}

// W16^k tables
__device__ __constant__ float TWC16[8] = {
    1.0f, 0.923879533f, 0.707106781f, 0.382683432f,
    0.0f, -0.382683432f, -0.707106781f, -0.923879533f };
__device__ __constant__ float TWS16[8] = {
    0.0f, 0.382683432f, 0.707106781f, 0.923879533f,
    1.0f, 0.923879533f, 0.707106781f, 0.382683432f };
// cross-8 stage-A twiddle fA(c) = (c<4) ? 1 : W8^(c-4)
__device__ __constant__ float FA_RE[8] = {1,1,1,1, 1.0f,  0.707106781f,  0.0f, -0.707106781f};
__device__ __constant__ float FA_IM[8] = {0,0,0,0, 0.0f, -0.707106781f, -1.0f, -0.707106781f};

// ---- local 16-point FFT in registers ---------------------------------------
__device__ __forceinline__ void fft16_fwd(float2 v[16]) {
    #pragma unroll
    for (int s = 8; s >= 1; s >>= 1) {
        #pragma unroll
        for (int q = 0; q < 16; q += 2 * s) {
            #pragma unroll
            for (int j = 0; j < s; j++) {
                const int tw = j * (8 / s);
                float2 u = v[q + j], w = v[q + j + s];
                v[q + j] = make_float2(u.x + w.x, u.y + w.y);
                float dx = u.x - w.x, dy = u.y - w.y;
                v[q + j + s] = make_float2(fmaf(dx, TWC16[tw],  dy * TWS16[tw]),
                                           fmaf(dy, TWC16[tw], -dx * TWS16[tw]));
            }
        }
    }
}
__device__ __forceinline__ void fft16_inv(float2 v[16]) {
    #pragma unroll
    for (int s = 1; s <= 8; s <<= 1) {
        #pragma unroll
        for (int q = 0; q < 16; q += 2 * s) {
            #pragma unroll
            for (int j = 0; j < s; j++) {
                const int tw = j * (8 / s);
                float2 u = v[q + j], w = v[q + j + s];
                float2 tv = make_float2(fmaf(w.x, TWC16[tw], -w.y * TWS16[tw]),
                                        fmaf(w.y, TWC16[tw],  w.x * TWS16[tw]));
                v[q + j]     = make_float2(u.x + tv.x, u.y + tv.y);
                v[q + j + s] = make_float2(u.x - tv.x, u.y - tv.y);
            }
        }
    }
}

// ---- cross-thread DFT8 over sub-index c (shfl_xor 4,2,1) -------------------
// fwd: natural in, output at thread br3(c). inv: br3-in, natural out (unnorm).
__device__ __forceinline__ void cross8_fwd(float2 v[16], int c, float2 fA) {
    const float sA = (c < 4) ? 1.0f : -1.0f;
    const float sB = (c & 2) ? -1.0f : 1.0f;
    const float sC = (c & 1) ? -1.0f : 1.0f;
    const bool rot3 = ((c & 3) == 3);
    #pragma unroll
    for (int p = 0; p < 16; p++) {
        float ox = __shfl_xor(v[p].x, 4), oy = __shfl_xor(v[p].y, 4);
        float ax = fmaf(sA, v[p].x, ox), ay = fmaf(sA, v[p].y, oy);
        float bx = fmaf(ax, fA.x, -ay * fA.y);
        float by = fmaf(ax, fA.y,  ay * fA.x);
        ox = __shfl_xor(bx, 2); oy = __shfl_xor(by, 2);
        float nx = fmaf(sB, bx, ox), ny = fmaf(sB, by, oy);
        float rx = rot3 ?  ny : nx;
        float ry = rot3 ? -nx : ny;
        ox = __shfl_xor(rx, 1); oy = __shfl_xor(ry, 1);
        v[p].x = fmaf(sC, rx, ox); v[p].y = fmaf(sC, ry, oy);
    }
}
__device__ __forceinline__ void cross8_inv(float2 v[16], int c, float2 fA) {
    const float sA = (c < 4) ? 1.0f : -1.0f;
    const float sB = (c & 2) ? -1.0f : 1.0f;
    const float sC = (c & 1) ? -1.0f : 1.0f;
    const bool rot3 = ((c & 3) == 3);
    #pragma unroll
    for (int p = 0; p < 16; p++) {
        float ox = __shfl_xor(v[p].x, 1), oy = __shfl_xor(v[p].y, 1);
        float nx = fmaf(sC, v[p].x, ox), ny = fmaf(sC, v[p].y, oy);
        float rx = rot3 ? -ny : nx;
        float ry = rot3 ?  nx : ny;
        ox = __shfl_xor(rx, 2); oy = __shfl_xor(ry, 2);
        float bx = fmaf(sB, rx, ox), by = fmaf(sB, ry, oy);
        float ax = fmaf(bx, fA.x,  by * fA.y);
        float ay = fmaf(by, fA.x, -bx * fA.y);
        ox = __shfl_xor(ax, 4); oy = __shfl_xor(ay, 4);
        v[p].x = fmaf(sA, ax, ox); v[p].y = fmaf(sA, ay, oy);
    }
}

// ---- pass A (local-first): input reg i = elem c+8i; out reg p = BR4(p)+16rc
// tA[8p+c] = W128^(c*BR4(p))  (broadcast-read, conflict-free)
__device__ __forceinline__ void pass_A_fwd(float2 v[16], int c, float2 fA,
                                           const float2* tA) {
    fft16_fwd(v);
    #pragma unroll
    for (int p = 0; p < 16; p++) v[p] = cmul(v[p], tA[8 * p + c]);
    cross8_fwd(v, c, fA);
}
__device__ __forceinline__ void pass_A_inv(float2 v[16], int c, float2 fA,
                                           const float2* tA) {
    cross8_inv(v, c, fA);
    #pragma unroll
    for (int p = 0; p < 16; p++) {
        float2 w = tA[8 * p + c];
        v[p] = cmul(v[p], make_float2(w.x, -w.y));
    }
    fft16_inv(v);
}

// ---- pass B (cross-first): input reg i = elem i+16c; out: thread holds
// k1=br3(c) (low 3 bits of k), reg p holds k2=BR4(p) (k = k1 + 8*k2).
// tB[8i+c] = W128^(i*br3(c))
__device__ __forceinline__ void pass_B_fwd(float2 v[16], int c, float2 fA,
                                           const float2* tB) {
    cross8_fwd(v, c, fA);
    #pragma unroll
    for (int i = 0; i < 16; i++) v[i] = cmul(v[i], tB[8 * i + c]);
    fft16_fwd(v);
}
__device__ __forceinline__ void pass_B_inv(float2 v[16], int c, float2 fA,
                                           const float2* tB) {
    fft16_inv(v);
    #pragma unroll
    for (int i = 0; i < 16; i++) {
        float2 w = tB[8 * i + c];
        v[i] = cmul(v[i], make_float2(w.x, -w.y));
    }
    cross8_inv(v, c, fA);
}

// ---- main kernel: one block per position; 2 blocks/CU (72.7KB LDS) ---------
// Transpose buffer in fp16 (__half2) with analytically conflict-free layout:
// addr(maj,min) = maj*136 + (rho(min) ^ (maj>>4)), rho = 7-bit rotl-3.
// All 4 transpose phases: 32 distinct banks, 2 lanes/bank (free floor).
__global__ void
__attribute__((amdgpu_flat_work_group_size(1024, 1024)))
multislice_kernel(const float* __restrict__ probe_re,
                  const float* __restrict__ probe_im,
                  const float* __restrict__ obj_re,
                  const float* __restrict__ obj_im,
                  const int*   __restrict__ positions,
                  float*       __restrict__ out)
{
    __shared__ __half2 LTH[128 * LSTR];   // 69632 B transpose buffer (fp16)
    __shared__ float2  tA[128];           // pass-A twiddle [8p+c]
    __shared__ float2  tB[128];           // pass-B twiddle [8i+c]
    __shared__ float2  pytp[128];         // prop y-factor/16384, kh=br3(c)+8BR4(p)

    const int t  = threadIdx.x;
    const int g  = t >> 3;                      // row (R) / col (C) index
    const int c  = t & 7;
    const int rc = BR3(c);
    const int gh = g >> 4;                      // sigma(g)
    const int rho_g = ((g & 15) << 3) | gh;     // rho(g)
    const int n  = blockIdx.x;
    const int Y0 = positions[2 * n];
    const int X0 = positions[2 * n + 1];

    if (t < 128) {
        int p_ = t >> 3, c_ = t & 7;
        float angA = -2.0f * 3.14159265358979323846f
                     * (float)(c_ * BR4(p_)) / 128.0f;
        float s, cc; __sincosf(angA, &s, &cc);
        tA[t] = make_float2(cc, s);
        float angB = -2.0f * 3.14159265358979323846f
                     * (float)(p_ * BR3(c_)) / 128.0f;
        __sincosf(angB, &s, &cc);
        tB[t] = make_float2(cc, s);
        int kh = BR3(c_) + 8 * BR4(p_);
        float fy = (float)(kh < 64 ? kh : kh - 128) * (1.0f / 25.6f);
        float ph = -0.15707963267948966f * fy * fy;
        float ps, pcs; __sincosf(ph, &ps, &pcs);
        pytp[t] = make_float2(pcs * (1.0f / 16384.0f), ps * (1.0f / 16384.0f));
    }
    const float2 fA = make_float2(FA_RE[c], FA_IM[c]);
    float fx = (float)(g < 64 ? g : g - 128) * (1.0f / 25.6f);
    float phx = -0.15707963267948966f * fx * fx;
    float pxs, pxc; __sincosf(phx, &pxs, &pxc);
    const float2 px = make_float2(pxc, pxs);
    __syncthreads();

    const long long base = (long long)n * NPIX;
    // precomputed transpose address bases
    const int a1w = rho_g ^ rc;        // T1-write minor (const per thread)
    const int a1r = g * LSTR + (c ^ gh);           // + 8i
    const int a2w = rho_g ^ c;         // T2-write minor
    const int a2r = g * LSTR + (rc ^ gh);          // + 8*BR4(p)

    float2 v[16];

    for (int m = 0; m < NMODES; m++) {
        __syncthreads();   // protect LTH reuse across modes
        #pragma unroll
        for (int i = 0; i < 16; i++) {           // ex = probe[m]*patch(slice0)
            int w  = c + 8 * i;
            int pi = m * NPIX + g * 128 + w;
            float2 pr = make_float2(probe_re[pi], probe_im[pi]);
            int oi = (Y0 + g) * OBJW + X0 + w;
            float2 ob = make_float2(obj_re[oi], obj_im[oi]);
            v[i] = cmul(pr, ob);
        }

        for (int s = 1; s < NSLICES; s++) {
            pass_A_fwd(v, c, fA, tA);            // Fw: reg p -> kw=BR4(p)+16rc
            #pragma unroll                       // T1 write [kw][r=g]
            for (int p = 0; p < 16; p++) {
                int kw = BR4(p) + 16 * rc;
                LTH[kw * LSTR + a1w] = __float22half2_rn(v[p]);
            }
            __syncthreads();
            #pragma unroll                       // T1 read -> C: reg i = row i+16c
            for (int i = 0; i < 16; i++)
                v[i] = __half22float2(LTH[a1r + 8 * i]);
            __syncthreads();
            pass_B_fwd(v, c, fA, tB);            // Fh: kh = br3(c)+8*BR4(p)
            #pragma unroll                       // * prop
            for (int p = 0; p < 16; p++) {
                float2 pp = cmul(pytp[8 * p + c], px);
                v[p] = cmul(v[p], pp);
            }
            pass_B_inv(v, c, fA, tB);            // iFh: reg i = row i+16c
            #pragma unroll                       // T2 write [r=i+16c][g]
            for (int i = 0; i < 16; i++)
                LTH[(i + 16 * c) * LSTR + a2w] = __float22half2_rn(v[i]);
            __syncthreads();
            #pragma unroll                       // T2 read -> R: reg p = kw
            for (int p = 0; p < 16; p++)
                v[p] = __half22float2(LTH[a2r + 8 * BR4(p)]);
            __syncthreads();
            pass_A_inv(v, c, fA, tA);            // iFw: natural w = c+8i
            #pragma unroll                       // * patch(slice s)
            for (int i = 0; i < 16; i++) {
                int w  = c + 8 * i;
                int oi = (s * OBJW + Y0 + g) * OBJW + X0 + w;
                float2 ob = make_float2(obj_re[oi], obj_im[oi]);
                v[i] = cmul(v[i], ob);
            }
        }

        // final FFT2: Fw, T1, Fh(pass_B), |.|^2 RMW into out
        pass_A_fwd(v, c, fA, tA);
        #pragma unroll
        for (int p = 0; p < 16; p++) {
            int kw = BR4(p) + 16 * rc;
            LTH[kw * LSTR + a1w] = __float22half2_rn(v[p]);
        }
        __syncthreads();
        #pragma unroll
        for (int i = 0; i < 16; i++)
            v[i] = __half22float2(LTH[a1r + 8 * i]);
        pass_B_fwd(v, c, fA, tB);
        // fftshift: (kh,kw)->(kh^64,kw^64); kh=br3(c)+8BR4(p), kw=g.
        // Same thread owns the same slots every mode -> plain RMW, no race.
        #pragma unroll
        for (int p = 0; p < 16; p++) {
            int kh = BR3(c) + 8 * BR4(p);
            long long oidx = base + (long long)(((kh ^ 64) << 7) + (g ^ 64));
            float val = fmaf(v[p].x, v[p].x, v[p].y * v[p].y);
            if (m > 0) val += out[oidx];
            out[oidx] = val;
        }
    }
}

extern "C" void kernel_launch(void* const* d_in, const int* in_sizes, int n_in,
                              void* d_out, int out_size, void* d_ws, size_t ws_size,
                              hipStream_t stream) {
    const float* probe_re = (const float*)d_in[0];
    const float* probe_im = (const float*)d_in[1];
    const float* obj_re   = (const float*)d_in[2];
    const float* obj_im   = (const float*)d_in[3];
    const int*   pos      = (const int*)d_in[4];
    float* out = (float*)d_out;

    const int N = out_size / NPIX;   // 512 positions
    multislice_kernel<<<dim3(N), dim3(NT), 0, stream>>>(
        probe_re, probe_im, obj_re, obj_im, pos, out);
}